// Round 11
// baseline (104.442 us; speedup 1.0000x reference)
//
#include <hip/hip_runtime.h>
#include <hip/hip_bf16.h>
#include <math.h>

#define D 64
#define H 4
#define NB 4
#define PAD 128
#define NEG_SLOPE 0.2f

typedef __attribute__((ext_vector_type(8))) short short8;
typedef __attribute__((ext_vector_type(4))) float f32x4;

__device__ __forceinline__ unsigned short f2bf(float f) {
    union { float f; unsigned int u; } c; c.f = f;
    const unsigned int u = c.u;
    return (unsigned short)((u + 0x7fffu + ((u >> 16) & 1u)) >> 16);
}

// ---- prep: [0,nq8) LDS-staged QKV (8 nodes/block) + zero rowFill ; [nq8,nq8+128) weight prepack ----
__global__ __launch_bounds__(256) void prep_kernel(
    const float* __restrict__ emb,
    const float* __restrict__ Qw, const float* __restrict__ Qb,
    const float* __restrict__ Kw, const float* __restrict__ Kb,
    const float* __restrict__ Vw, const float* __restrict__ Vb,
    unsigned short* __restrict__ Qbf, unsigned short* __restrict__ Kbf,
    float* __restrict__ V,
    const float* __restrict__ W0, const float* __restrict__ W1,
    unsigned short* __restrict__ W0p, unsigned short* __restrict__ W1p,
    int* __restrict__ rowFill, int N, int nq8)
{
    __shared__ __align__(16) unsigned char pbuf[51200];
    const int tid = threadIdx.x;
    const int bid = blockIdx.x;
    if (bid < nq8) {
        float* wq = (float*)pbuf;
        float* wk = (float*)(pbuf + 16384);
        float* wv = (float*)(pbuf + 32768);
        float* et = (float*)(pbuf + 49152);   // 8 x 64
        const int base_n = bid * 8;
        if (tid < 8 && base_n + tid < N) rowFill[base_n + tid] = 0;
        {
            const float4* q4 = (const float4*)Qw;
            const float4* k4 = (const float4*)Kw;
            const float4* v4 = (const float4*)Vw;
            float4* wq4 = (float4*)wq;
            float4* wk4 = (float4*)wk;
            float4* wv4 = (float4*)wv;
            for (int i = tid; i < 1024; i += 256) {
                wq4[i] = q4[i];
                wk4[i] = k4[i];
                wv4[i] = v4[i];
            }
        }
        for (int i = tid; i < 512; i += 256) {
            const int n = base_n + (i >> 6);
            et[i] = (n < N) ? emb[n * D + (i & 63)] : 0.f;
        }
        __syncthreads();
        const int lane = tid & 63, wave = tid >> 6;
        const int d = lane;
#pragma unroll
        for (int r = 0; r < 2; ++r) {
            const int li = r * 4 + wave;
            const int n = base_n + li;
            if (n < N) {
                float aq = Qb[d], ak = Kb[d], av = Vb[d];
                const float* er = et + li * 64;
#pragma unroll 8
                for (int k = 0; k < D; ++k) {
                    const float x = er[k];
                    aq += x * wq[k * D + d];
                    ak += x * wk[k * D + d];
                    av += x * wv[k * D + d];
                }
                Qbf[n * D + d] = f2bf(aq);
                Kbf[n * D + d] = f2bf(ak);
                V[n * D + d] = av;
            }
        }
    } else {
        const int base = (bid - nq8) * 1024;
#pragma unroll
        for (int kk = 0; kk < 4; ++kk) {
            const int idx = base + kk * 256 + tid;   // < 131072
            const int j = idx & 7, ln = (idx >> 3) & 63, nt = (idx >> 9) & 3;
            const int ks = (idx >> 11) & 3, bh = idx >> 13;
            const int k = ks * 32 + ((ln >> 4) << 3) + j;
            const int nn = (nt << 4) + (ln & 15);
            W0p[idx] = f2bf(W0[((size_t)bh * 128 + k) * 64 + nn]);
        }
        const int base1 = (bid - nq8) * 512;
#pragma unroll
        for (int kk = 0; kk < 2; ++kk) {
            const int idx = base1 + kk * 256 + tid;  // < 65536
            const int j = idx & 7, ln = (idx >> 3) & 63, nt = (idx >> 9) & 3;
            const int ks = (idx >> 11) & 1, bh = idx >> 12;
            const int k = ks * 32 + ((ln >> 4) << 3) + j;
            const int nn = (nt << 4) + (ln & 15);
            W1p[idx] = f2bf(W1[((size_t)bh * 64 + k) * 64 + nn]);
        }
    }
}

// ---- mlp: blocks [0, nblk*NB) self-group a (chunk,bond) and run MFMA sub-tiles;
//          blocks [nblk*NB, nblk*NB+nblk) do the row-scatter (padded row lists) ----
__global__ __launch_bounds__(256) void mlp_kernel(
    const unsigned short* __restrict__ Qbf, const unsigned short* __restrict__ Kbf,
    const int* __restrict__ src, const int* __restrict__ dst,
    const int* __restrict__ bond, int Ep, int TE, int nblk,
    int* __restrict__ rowFill, int* __restrict__ edge_col, int* __restrict__ edge_eid,
    const unsigned short* __restrict__ W0p, const unsigned short* __restrict__ W1p,
    const float* __restrict__ b0, const float* __restrict__ b1,
    const float* __restrict__ W2, const float* __restrict__ b2,
    float* __restrict__ S)
{
    const int tid = threadIdx.x;
    const int lane = tid & 63, wave = tid >> 6;

    if (blockIdx.x >= nblk * NB) {
        // ---- row-scatter chunk ----
        const int vb = blockIdx.x - nblk * NB;
        const int e = vb * 256 + tid;
        if (e < TE) {
            int sN, dN;
            if (e < Ep) { sN = src[e]; dN = dst[e]; }
            else        { sN = dst[e - Ep]; dN = src[e - Ep]; }
            const int p = atomicAdd(&rowFill[sN], 1);
            if (p < PAD) {
                edge_col[sN * PAD + p] = dN;
                edge_eid[sN * PAD + p] = e;
            }
        }
        return;
    }

    // ---- group block: chunk vb, bond bt ----
    const int bt = blockIdx.x & (NB - 1);
    const int vb = blockIdx.x >> 2;

    __shared__ __align__(16) unsigned char buf[32768];
    __shared__ int glist[256];
    __shared__ int wbase[5];

    {
        const int e = vb * 256 + tid;
        int bmatch = 0;
        if (e < TE) bmatch = ((e < Ep ? bond[e] : bond[e - Ep]) == bt) ? 1 : 0;
        const unsigned long long m = __ballot(bmatch != 0);
        const int rank = (int)__popcll(m & ((1ull << lane) - 1ull));
        if (lane == 0) wbase[wave + 1] = (int)__popcll(m);
        __syncthreads();
        if (tid == 0) {
            wbase[0] = 0;
            for (int w_ = 1; w_ <= 4; ++w_) wbase[w_] += wbase[w_ - 1];
        }
        __syncthreads();
        if (bmatch) glist[wbase[wave] + rank] = e;
    }
    __syncthreads();
    const int ne_all = wbase[4];
    if (ne_all == 0) return;

    const int h = wave;
    const int bh = bt * H + h;
    const int lg = lane >> 4;
    const int lr = lane & 15;
    const int e_w = ((lr >> 2) << 4) + (lg << 2) + (lr & 3);

    const short8* W0f = (const short8*)W0p + (size_t)bh * 1024;
    const short8* W1f = (const short8*)W1p + (size_t)bh * 512;
    const float* bb0 = b0 + bh * 64;
    const float* bb1 = b1 + bh * 64;
    const float* w2 = W2 + bh * 64;
    float w2v[4];
#pragma unroll
    for (int nt = 0; nt < 4; ++nt) w2v[nt] = w2[(nt << 4) + lr];
    const float b2v = b2[bh];

    for (int st = 0; st * 64 < ne_all; ++st) {
        const int ne = min(64, ne_all - st * 64);
        __syncthreads();   // protect buf reuse across sub-tiles

        // gather x = [Q[s] | K[d]] bf16 into swizzled xs = buf[0:16K)
        for (int i = tid; i < 1024; i += 256) {
            const int el = i >> 4, u = i & 15;
            uint4 v = make_uint4(0, 0, 0, 0);
            if (el < ne) {
                const int e = glist[st * 64 + el];
                int s, d;
                if (e < Ep) { s = src[e]; d = dst[e]; }
                else        { s = dst[e - Ep]; d = src[e - Ep]; }
                v = (u < 8) ? ((const uint4*)(Qbf + s * 64))[u]
                            : ((const uint4*)(Kbf + d * 64))[u - 8];
            }
            const int b = (el << 8) + (u << 4);
            *(uint4*)(buf + (b ^ ((el & 7) << 4))) = v;
        }
        __syncthreads();

        // ---- layer 0: H0 = relu(X @ W0 + b0), K=128 ----
        f32x4 acc[4][4];
#pragma unroll
        for (int nt = 0; nt < 4; ++nt) {
            const float bv = bb0[(nt << 4) + lr];
#pragma unroll
            for (int mt = 0; mt < 4; ++mt) acc[mt][nt] = (f32x4){bv, bv, bv, bv};
        }
#pragma unroll
        for (int ks = 0; ks < 4; ++ks) {
            short8 a[4];
            const int koff = (ks << 6) + (lg << 4);
#pragma unroll
            for (int mt = 0; mt < 4; ++mt) {
                const int row = (mt << 4) + lr;
                const int b = (row << 8) + koff;
                a[mt] = *(const short8*)(buf + (b ^ ((row & 7) << 4)));
            }
            short8 bfr[4];
#pragma unroll
            for (int nt = 0; nt < 4; ++nt) bfr[nt] = W0f[(((ks << 2) + nt) << 6) + lane];
#pragma unroll
            for (int mt = 0; mt < 4; ++mt)
#pragma unroll
                for (int nt = 0; nt < 4; ++nt)
                    acc[mt][nt] = __builtin_amdgcn_mfma_f32_16x16x32_bf16(a[mt], bfr[nt], acc[mt][nt], 0, 0, 0);
        }
        // all waves done reading xs; overlay per-wave H0 (bf16, swizzled)
        __syncthreads();
        unsigned char* h0 = buf + h * 8192;
#pragma unroll
        for (int mt = 0; mt < 4; ++mt)
#pragma unroll
            for (int nt = 0; nt < 4; ++nt)
#pragma unroll
                for (int r = 0; r < 4; ++r) {
                    const int row = (mt << 4) + (lg << 2) + r;
                    const int col = (nt << 4) + lr;
                    const int b = (row << 7) + (col << 1);
                    *(unsigned short*)(h0 + (b ^ ((row & 7) << 4))) = f2bf(fmaxf(acc[mt][nt][r], 0.f));
                }

        // ---- layer 1: H1 = relu(H0 @ W1 + b1), K=64 ----
        f32x4 acc1[4][4];
#pragma unroll
        for (int nt = 0; nt < 4; ++nt) {
            const float bv = bb1[(nt << 4) + lr];
#pragma unroll
            for (int mt = 0; mt < 4; ++mt) acc1[mt][nt] = (f32x4){bv, bv, bv, bv};
        }
#pragma unroll
        for (int ks = 0; ks < 2; ++ks) {
            short8 a[4];
            const int koff = (ks << 6) + (lg << 4);
#pragma unroll
            for (int mt = 0; mt < 4; ++mt) {
                const int row = (mt << 4) + lr;
                const int b = (row << 7) + koff;
                a[mt] = *(const short8*)(h0 + (b ^ ((row & 7) << 4)));
            }
            short8 bfr[4];
#pragma unroll
            for (int nt = 0; nt < 4; ++nt) bfr[nt] = W1f[(((ks << 2) + nt) << 6) + lane];
#pragma unroll
            for (int mt = 0; mt < 4; ++mt)
#pragma unroll
                for (int nt = 0; nt < 4; ++nt)
                    acc1[mt][nt] = __builtin_amdgcn_mfma_f32_16x16x32_bf16(a[mt], bfr[nt], acc1[mt][nt], 0, 0, 0);
        }

        // ---- layer 2 + leaky relu; 16-lane reduce; write S[e*H+h] ----
        float p[4][4];
#pragma unroll
        for (int mt = 0; mt < 4; ++mt)
#pragma unroll
            for (int r = 0; r < 4; ++r) {
                float s = 0.f;
#pragma unroll
                for (int nt = 0; nt < 4; ++nt) s += fmaxf(acc1[mt][nt][r], 0.f) * w2v[nt];
                p[mt][r] = s;
            }
#pragma unroll
        for (int off = 1; off <= 8; off <<= 1)
#pragma unroll
            for (int mt = 0; mt < 4; ++mt)
#pragma unroll
                for (int r = 0; r < 4; ++r) p[mt][r] += __shfl_xor(p[mt][r], off, 64);
        float sc = p[lr >> 2][lr & 3] + b2v;
        sc = sc > 0.f ? sc : NEG_SLOPE * sc;
        if (e_w < ne) S[(size_t)glist[st * 64 + e_w] * H + h] = sc;
    }
}

// ---- agg: padded rows; scores by edge id; softmax per head-wave; shared-V PV; fused projection ----
__global__ __launch_bounds__(256) void agg_kernel(
    const float* __restrict__ V, const float* __restrict__ S,
    const int* __restrict__ rowFill,
    const int* __restrict__ edge_col, const int* __restrict__ edge_eid,
    const float* __restrict__ Pw, const float* __restrict__ Pb, float* __restrict__ out)
{
    const int row = blockIdx.x;
    const int tid = threadIdx.x;
    const int lane = tid & 63;
    const int wv = tid >> 6;
    const int beg = row * PAD;
    int deg = rowFill[row];
    if (deg > PAD) deg = PAD;

    __shared__ int tcol[PAD], teid[PAD], scol[PAD], seid[PAD], win[PAD];
    __shared__ float wgt[4][PAD];
    __shared__ float sdn[4];
    __shared__ float partv[4][4][64];
    __shared__ float rr[256];
    __shared__ float part2[4][64];

    for (int a = tid; a < deg; a += 256) { tcol[a] = edge_col[beg + a]; teid[a] = edge_eid[beg + a]; }
    __syncthreads();
    for (int a = tid; a < deg; a += 256) {
        const int e = teid[a];
        int r = 0;
        for (int b = 0; b < deg; ++b) r += (teid[b] < e);
        scol[r] = tcol[a];
        seid[r] = e;
    }
    __syncthreads();
    for (int a = tid; a < deg; a += 256) {
        const int c = scol[a];
        int wn = 1;
        for (int b = a + 1; b < deg; ++b) if (scol[b] == c) { wn = 0; break; }
        win[a] = wn;
    }
    __syncthreads();

    // softmax: wave wv handles head wv
    float m = -1e30f;
    for (int a = lane; a < deg; a += 64)
        if (win[a]) m = fmaxf(m, S[(size_t)seid[a] * H + wv]);
#pragma unroll
    for (int off = 32; off; off >>= 1) m = fmaxf(m, __shfl_xor(m, off, 64));

    float dn = 0.f;
    for (int a = lane; a < deg; a += 64) {
        const float wvv = win[a] ? __expf(S[(size_t)seid[a] * H + wv] - m) : 0.f;
        wgt[wv][a] = wvv;
        dn += wvv;
    }
#pragma unroll
    for (int off = 32; off; off >>= 1) dn += __shfl_xor(dn, off, 64);
    if (lane == 0) sdn[wv] = dn;
    __syncthreads();

    // PV: wave wv covers edges a = wv, wv+4, ...; each V row loaded once, used by all 4 heads
    float pv0 = 0.f, pv1 = 0.f, pv2 = 0.f, pv3 = 0.f;
    for (int a = wv; a < deg; a += 4) {
        const float vr = V[(size_t)scol[a] * D + lane];
        pv0 += wgt[0][a] * vr;
        pv1 += wgt[1][a] * vr;
        pv2 += wgt[2][a] * vr;
        pv3 += wgt[3][a] * vr;
    }
    partv[wv][0][lane] = pv0;
    partv[wv][1][lane] = pv1;
    partv[wv][2][lane] = pv2;
    partv[wv][3][lane] = pv3;
    __syncthreads();

    rr[wv * 64 + lane] = (partv[0][wv][lane] + partv[1][wv][lane]
                        + partv[2][wv][lane] + partv[3][wv][lane]) / sdn[wv];
    __syncthreads();

    {
        float sps = 0.f;
#pragma unroll 8
        for (int k = 0; k < 64; ++k) sps += rr[wv * 64 + k] * Pw[(wv * 64 + k) * D + lane];
        part2[wv][lane] = sps;
    }
    __syncthreads();
    if (tid < 64)
        out[(size_t)row * D + tid] = part2[0][tid] + part2[1][tid] + part2[2][tid] + part2[3][tid] + Pb[tid];
}

extern "C" void kernel_launch(void* const* d_in, const int* in_sizes, int n_in,
                              void* d_out, int out_size, void* d_ws, size_t ws_size,
                              hipStream_t stream)
{
    const float* emb = (const float*)d_in[0];
    const float* Qw  = (const float*)d_in[1];
    const float* Qb  = (const float*)d_in[2];
    const float* Kw  = (const float*)d_in[3];
    const float* Kb  = (const float*)d_in[4];
    const float* Vw  = (const float*)d_in[5];
    const float* Vb  = (const float*)d_in[6];
    const float* W0  = (const float*)d_in[7];
    const float* b0  = (const float*)d_in[8];
    const float* W1  = (const float*)d_in[9];
    const float* b1  = (const float*)d_in[10];
    const float* W2  = (const float*)d_in[11];
    const float* b2  = (const float*)d_in[12];
    const float* Pw  = (const float*)d_in[13];
    const float* Pb  = (const float*)d_in[14];
    const int* src   = (const int*)d_in[15];
    const int* dst   = (const int*)d_in[16];
    const int* bond  = (const int*)d_in[17];

    const int N  = in_sizes[0] / D;
    const int Ep = in_sizes[15];
    const int TE = 2 * Ep;
    const int nblk = (TE + 255) / 256;
    const int nq8 = (N + 7) / 8;

    char* w = (char*)d_ws;
    auto alloc = [&](size_t bytes) -> void* {
        void* p = (void*)w;
        w += ((bytes + 255) / 256) * 256;
        return p;
    };
    unsigned short* Qbf = (unsigned short*)alloc((size_t)N * D * 2);
    unsigned short* Kbf = (unsigned short*)alloc((size_t)N * D * 2);
    float* V        = (float*)alloc((size_t)N * D * 4);
    unsigned short* W0p = (unsigned short*)alloc((size_t)131072 * 2);
    unsigned short* W1p = (unsigned short*)alloc((size_t)65536 * 2);
    float* S        = (float*)alloc((size_t)TE * H * 4);
    int* edge_col   = (int*)alloc((size_t)N * PAD * 4);
    int* edge_eid   = (int*)alloc((size_t)N * PAD * 4);
    int* rowFill    = (int*)alloc((size_t)N * 4);
    if ((size_t)(w - (char*)d_ws) > ws_size) return;

    prep_kernel<<<nq8 + 128, 256, 0, stream>>>(
        emb, Qw, Qb, Kw, Kb, Vw, Vb, Qbf, Kbf, V, W0, W1, W0p, W1p,
        rowFill, N, nq8);
    mlp_kernel<<<nblk * NB + nblk, 256, 0, stream>>>(
        Qbf, Kbf, src, dst, bond, Ep, TE, nblk,
        rowFill, edge_col, edge_eid,
        W0p, W1p, b0, b1, W2, b2, S);
    agg_kernel<<<N, 256, 0, stream>>>(
        V, S, rowFill, edge_col, edge_eid, Pw, Pb, (float*)d_out);
}

// Round 12
// 77.110 us; speedup vs baseline: 1.3545x; 1.3545x over previous
//
#include <hip/hip_runtime.h>
#include <hip/hip_bf16.h>
#include <math.h>

#define D 64
#define H 4
#define NB 4
#define TILE 64
#define PAD 128
#define NEG_SLOPE 0.2f

typedef __attribute__((ext_vector_type(8))) short short8;
typedef __attribute__((ext_vector_type(4))) float f32x4;

__device__ __forceinline__ unsigned short f2bf(float f) {
    union { float f; unsigned int u; } c; c.f = f;
    const unsigned int u = c.u;
    return (unsigned short)((u + 0x7fffu + ((u >> 16) & 1u)) >> 16);
}

// ---- prep: [0,nq8) LDS-staged QKV (8 nodes/block) + zero rowFill ;
//            [nq8,nq8+128) weight prepack (dense) ; [nq8+128,..) bond histogram (4 chunks/block) ----
__global__ __launch_bounds__(256) void prep_kernel(
    const float* __restrict__ emb,
    const float* __restrict__ Qw, const float* __restrict__ Qb,
    const float* __restrict__ Kw, const float* __restrict__ Kb,
    const float* __restrict__ Vw, const float* __restrict__ Vb,
    unsigned short* __restrict__ Qbf, unsigned short* __restrict__ Kbf,
    float* __restrict__ V,
    const float* __restrict__ W0, const float* __restrict__ W1,
    unsigned short* __restrict__ W0p, unsigned short* __restrict__ W1p,
    const int* __restrict__ bond, int Ep, int TE,
    int* __restrict__ rowFill, int* __restrict__ blockBondCnt, int nblk,
    int N, int nq8)
{
    // segA layout: wq[0:16K) wk[16K:32K) wv[32K:48K) et[48K:50K)
    __shared__ __align__(16) unsigned char pbuf[51200];
    const int tid = threadIdx.x;
    const int bid = blockIdx.x;
    if (bid < nq8) {
        float* wq = (float*)pbuf;
        float* wk = (float*)(pbuf + 16384);
        float* wv = (float*)(pbuf + 32768);
        float* et = (float*)(pbuf + 49152);   // 8 x 64
        const int base_n = bid * 8;
        if (tid < 8 && base_n + tid < N) rowFill[base_n + tid] = 0;
        {
            const float4* q4 = (const float4*)Qw;
            const float4* k4 = (const float4*)Kw;
            const float4* v4 = (const float4*)Vw;
            float4* wq4 = (float4*)wq;
            float4* wk4 = (float4*)wk;
            float4* wv4 = (float4*)wv;
            for (int i = tid; i < 1024; i += 256) {
                wq4[i] = q4[i];
                wk4[i] = k4[i];
                wv4[i] = v4[i];
            }
        }
        for (int i = tid; i < 512; i += 256) {
            const int n = base_n + (i >> 6);
            et[i] = (n < N) ? emb[n * D + (i & 63)] : 0.f;
        }
        __syncthreads();
        const int lane = tid & 63, wave = tid >> 6;
        const int d = lane;
#pragma unroll
        for (int r = 0; r < 2; ++r) {
            const int li = r * 4 + wave;
            const int n = base_n + li;
            if (n < N) {
                float aq = Qb[d], ak = Kb[d], av = Vb[d];
                const float* er = et + li * 64;
#pragma unroll 8
                for (int k = 0; k < D; ++k) {
                    const float x = er[k];
                    aq += x * wq[k * D + d];
                    ak += x * wk[k * D + d];
                    av += x * wv[k * D + d];
                }
                Qbf[n * D + d] = f2bf(aq);
                Kbf[n * D + d] = f2bf(ak);
                V[n * D + d] = av;
            }
        }
    } else if (bid < nq8 + 128) {
        const int base = (bid - nq8) * 1024;
#pragma unroll
        for (int kk = 0; kk < 4; ++kk) {
            const int idx = base + kk * 256 + tid;   // < 131072
            const int j = idx & 7, ln = (idx >> 3) & 63, nt = (idx >> 9) & 3;
            const int ks = (idx >> 11) & 3, bh = idx >> 13;
            const int k = ks * 32 + ((ln >> 4) << 3) + j;
            const int nn = (nt << 4) + (ln & 15);
            W0p[idx] = f2bf(W0[((size_t)bh * 128 + k) * 64 + nn]);
        }
        const int base1 = (bid - nq8) * 512;
#pragma unroll
        for (int kk = 0; kk < 2; ++kk) {
            const int idx = base1 + kk * 256 + tid;  // < 65536
            const int j = idx & 7, ln = (idx >> 3) & 63, nt = (idx >> 9) & 3;
            const int ks = (idx >> 11) & 1, bh = idx >> 12;
            const int k = ks * 32 + ((ln >> 4) << 3) + j;
            const int nn = (nt << 4) + (ln & 15);
            W1p[idx] = f2bf(W1[((size_t)bh * 64 + k) * 64 + nn]);
        }
    } else {
        int* wcnt = (int*)pbuf;   // [4][NB]
        const int vb4 = bid - nq8 - 128;
        const int lane = tid & 63, wave = tid >> 6;
#pragma unroll
        for (int j = 0; j < 4; ++j) {
            const int vb = vb4 * 4 + j;
            if (vb >= nblk) break;
            const int e = vb * 256 + tid;
            int bt = -1;
            if (e < TE) bt = (e < Ep) ? bond[e] : bond[e - Ep];
#pragma unroll
            for (int t = 0; t < NB; ++t) {
                const unsigned long long m = __ballot(bt == t);
                if (lane == 0) wcnt[wave * NB + t] = (int)__popcll(m);
            }
            __syncthreads();
            if (tid < NB) {
                int s = 0;
#pragma unroll
                for (int w = 0; w < 4; ++w) s += wcnt[w * NB + tid];
                blockBondCnt[tid * nblk + vb] = s;
            }
            __syncthreads();
        }
    }
}

// ---- scatter: in-block scan of blockBondCnt -> bases; padded row lists + bond buckets;
//      block 0 also emits the exact tile list for mlp ----
__global__ __launch_bounds__(256) void scatter_kernel(
    const int* __restrict__ src, const int* __restrict__ dst,
    const int* __restrict__ bond, int Ep, int TE, int nblk,
    const int* __restrict__ blockBondCnt, int* __restrict__ rowFill,
    int* __restrict__ edge_col, int* __restrict__ edge_eid,
    int* __restrict__ padPos, int* __restrict__ bond_edges, int* __restrict__ bondOff,
    int* __restrict__ tileBt, int* __restrict__ tileT0, int* __restrict__ ntiles)
{
    __shared__ int chunkpre[256];
    __shared__ int base_lds[NB];
    __shared__ int wcnt[4][NB], wbase[4][NB];
    __shared__ int tpre[NB + 1];
    const int tid = threadIdx.x;
    const int vb = blockIdx.x;
    const int M = NB * nblk;
    const int c = (M + 255) >> 8;

    int s = 0;
    for (int i = 0; i < c; ++i) { const int idx = tid * c + i; if (idx < M) s += blockBondCnt[idx]; }
    chunkpre[tid] = s;
    __syncthreads();
    int val = s;
    for (int off = 1; off < 256; off <<= 1) {
        const int o = (tid >= off) ? chunkpre[tid - off] : 0;
        __syncthreads();
        val += o;
        chunkpre[tid] = val;
        __syncthreads();
    }
    int excl = val - s;
    for (int i = 0; i < c; ++i) {
        const int idx = tid * c + i;
        if (idx < M) {
            const int t = idx / nblk, r = idx - t * nblk;
            if (r == vb) base_lds[t] = excl;
            if (vb == 0 && r == 0) bondOff[t] = excl;
            excl += blockBondCnt[idx];
        }
    }
    if (vb == 0 && tid == 255) bondOff[NB] = chunkpre[255];
    __syncthreads();

    const int lane = tid & 63, wave = tid >> 6;
    const int e = vb * 256 + tid;
    const bool act = (e < TE);
    int sN = 0, dN = 0, bt = -1;
    if (act) {
        if (e < Ep) { sN = src[e]; dN = dst[e]; bt = bond[e]; }
        else        { sN = dst[e - Ep]; dN = src[e - Ep]; bt = bond[e - Ep]; }
        const int p = atomicAdd(&rowFill[sN], 1);
        if (p < PAD) {
            edge_col[sN * PAD + p] = dN;
            edge_eid[sN * PAD + p] = e;
            padPos[e] = sN * PAD + p;
        } else padPos[e] = -1;
    }
    int myrank = 0;
#pragma unroll
    for (int t = 0; t < NB; ++t) {
        const unsigned long long m = __ballot(bt == t);
        if (lane == 0) wcnt[wave][t] = (int)__popcll(m);
        if (bt == t) myrank = (int)__popcll(m & ((1ull << lane) - 1ull));
    }
    __syncthreads();
    if (tid < NB) {
        int sum = 0;
#pragma unroll
        for (int w = 0; w < 4; ++w) { wbase[w][tid] = sum; sum += wcnt[w][tid]; }
    }
    __syncthreads();
    if (act) bond_edges[base_lds[bt] + wbase[wave][bt] + myrank] = e;

    // block 0: exact tile list (bondOff written by this block before the earlier barrier)
    if (vb == 0) {
        if (tid == 0) {
            tpre[0] = 0;
            for (int b = 0; b < NB; ++b) {
                const int cntb = bondOff[b + 1] - bondOff[b];
                tpre[b + 1] = tpre[b] + ((cntb + 63) >> 6);
            }
            ntiles[0] = tpre[NB];
        }
        __syncthreads();
        for (int i = tid; i < tpre[NB]; i += 256) {
            int b = 0;
            while (i >= tpre[b + 1]) ++b;
            tileBt[i] = b;
            tileT0[i] = (i - tpre[b]) << 6;
        }
    }
}

// ---- MFMA grouped edge MLP over exact tile list (1-D grid, no empty dispatches) ----
__global__ __launch_bounds__(256) void mlp_kernel(
    const unsigned short* __restrict__ Qbf, const unsigned short* __restrict__ Kbf,
    const int* __restrict__ src, const int* __restrict__ dst, int Ep,
    const int* __restrict__ bondOff, const int* __restrict__ bond_edges,
    const int* __restrict__ padPos,
    const int* __restrict__ tileBt, const int* __restrict__ tileT0,
    const int* __restrict__ ntiles,
    const unsigned short* __restrict__ W0p, const unsigned short* __restrict__ W1p,
    const float* __restrict__ b0, const float* __restrict__ b1,
    const float* __restrict__ W2, const float* __restrict__ b2,
    float* __restrict__ S)
{
    const int vt = blockIdx.x;
    if (vt >= ntiles[0]) return;
    const int bt = tileBt[vt];
    const int t0 = tileT0[vt];
    const int base = bondOff[bt];
    const int cnt  = bondOff[bt + 1] - base;
    const int ne = min(TILE, cnt - t0);

    // union: xs = buf[0:16K) during gather+layer0; h0(wave w) = buf[w*8K : w*8K+8K) after
    __shared__ __align__(16) unsigned char buf[32768];
    __shared__ int eids[TILE];

    const int tid = threadIdx.x;
    if (tid < TILE) eids[tid] = (tid < ne) ? bond_edges[base + t0 + tid] : 0;
    __syncthreads();

    // gather x = [Q[s] | K[d]] bf16 into swizzled xs
    for (int i = tid; i < 1024; i += 256) {
        const int el = i >> 4, u = i & 15;
        uint4 v = make_uint4(0, 0, 0, 0);
        if (el < ne) {
            const int e = eids[el];
            int s, d;
            if (e < Ep) { s = src[e]; d = dst[e]; }
            else        { s = dst[e - Ep]; d = src[e - Ep]; }
            v = (u < 8) ? ((const uint4*)(Qbf + s * 64))[u]
                        : ((const uint4*)(Kbf + d * 64))[u - 8];
        }
        const int b = (el << 8) + (u << 4);
        *(uint4*)(buf + (b ^ ((el & 7) << 4))) = v;
    }

    const int lane = tid & 63;
    const int h = tid >> 6;
    const int bh = bt * H + h;
    const int lg = lane >> 4;
    const int lr = lane & 15;

    // prefetch the epilogue's padPos (independent of LDS) so its latency hides under layer 0
    const int e_w = ((lr >> 2) << 4) + (lg << 2) + (lr & 3);
    const int pp = (e_w < ne) ? padPos[eids[e_w]] : -1;
    __syncthreads();

    // ---- layer 0: H0 = relu(X @ W0 + b0), K=128 ----
    f32x4 acc[4][4];
    const float* bb0 = b0 + bh * 64;
#pragma unroll
    for (int nt = 0; nt < 4; ++nt) {
        const float bv = bb0[(nt << 4) + lr];
#pragma unroll
        for (int mt = 0; mt < 4; ++mt) acc[mt][nt] = (f32x4){bv, bv, bv, bv};
    }
    const short8* W0f = (const short8*)W0p + (size_t)bh * 1024;
#pragma unroll
    for (int ks = 0; ks < 4; ++ks) {
        short8 a[4];
        const int koff = (ks << 6) + (lg << 4);
#pragma unroll
        for (int mt = 0; mt < 4; ++mt) {
            const int row = (mt << 4) + lr;
            const int b = (row << 8) + koff;
            a[mt] = *(const short8*)(buf + (b ^ ((row & 7) << 4)));
        }
        short8 bfr[4];
#pragma unroll
        for (int nt = 0; nt < 4; ++nt) bfr[nt] = W0f[(((ks << 2) + nt) << 6) + lane];
#pragma unroll
        for (int mt = 0; mt < 4; ++mt)
#pragma unroll
            for (int nt = 0; nt < 4; ++nt)
                acc[mt][nt] = __builtin_amdgcn_mfma_f32_16x16x32_bf16(a[mt], bfr[nt], acc[mt][nt], 0, 0, 0);
    }
    // all waves have consumed xs; safe to overlay H0 onto it
    __syncthreads();
    unsigned char* h0 = buf + h * 8192;
#pragma unroll
    for (int mt = 0; mt < 4; ++mt)
#pragma unroll
        for (int nt = 0; nt < 4; ++nt)
#pragma unroll
            for (int r = 0; r < 4; ++r) {
                const int row = (mt << 4) + (lg << 2) + r;
                const int col = (nt << 4) + lr;
                const int b = (row << 7) + (col << 1);
                *(unsigned short*)(h0 + (b ^ ((row & 7) << 4))) = f2bf(fmaxf(acc[mt][nt][r], 0.f));
            }

    // ---- layer 1: H1 = relu(H0 @ W1 + b1), K=64 ----
    f32x4 acc1[4][4];
    const float* bb1 = b1 + bh * 64;
#pragma unroll
    for (int nt = 0; nt < 4; ++nt) {
        const float bv = bb1[(nt << 4) + lr];
#pragma unroll
        for (int mt = 0; mt < 4; ++mt) acc1[mt][nt] = (f32x4){bv, bv, bv, bv};
    }
    const short8* W1f = (const short8*)W1p + (size_t)bh * 512;
#pragma unroll
    for (int ks = 0; ks < 2; ++ks) {
        short8 a[4];
        const int koff = (ks << 6) + (lg << 4);
#pragma unroll
        for (int mt = 0; mt < 4; ++mt) {
            const int row = (mt << 4) + lr;
            const int b = (row << 7) + koff;
            a[mt] = *(const short8*)(h0 + (b ^ ((row & 7) << 4)));
        }
        short8 bfr[4];
#pragma unroll
        for (int nt = 0; nt < 4; ++nt) bfr[nt] = W1f[(((ks << 2) + nt) << 6) + lane];
#pragma unroll
        for (int mt = 0; mt < 4; ++mt)
#pragma unroll
            for (int nt = 0; nt < 4; ++nt)
                acc1[mt][nt] = __builtin_amdgcn_mfma_f32_16x16x32_bf16(a[mt], bfr[nt], acc1[mt][nt], 0, 0, 0);
    }

    // ---- layer 2 + leaky relu ----
    const float* w2 = W2 + bh * 64;
    float w2v[4];
#pragma unroll
    for (int nt = 0; nt < 4; ++nt) w2v[nt] = w2[(nt << 4) + lr];
    float p[4][4];
#pragma unroll
    for (int mt = 0; mt < 4; ++mt)
#pragma unroll
        for (int r = 0; r < 4; ++r) {
            float s = 0.f;
#pragma unroll
            for (int nt = 0; nt < 4; ++nt) s += fmaxf(acc1[mt][nt][r], 0.f) * w2v[nt];
            p[mt][r] = s;
        }
#pragma unroll
    for (int off = 1; off <= 8; off <<= 1)
#pragma unroll
        for (int mt = 0; mt < 4; ++mt)
#pragma unroll
            for (int r = 0; r < 4; ++r) p[mt][r] += __shfl_xor(p[mt][r], off, 64);
    float sc = p[lr >> 2][lr & 3] + b2[bh];
    sc = sc > 0.f ? sc : NEG_SLOPE * sc;
    if (e_w < ne && pp >= 0) S[(size_t)pp * H + h] = sc;
}

// ---- agg: padded rows; softmax per head-wave; PV split across waves by edge; fused projection ----
__global__ __launch_bounds__(256) void agg_kernel(
    const float* __restrict__ V, const float* __restrict__ S,
    const int* __restrict__ rowFill,
    const int* __restrict__ edge_col, const int* __restrict__ edge_eid,
    const float* __restrict__ Pw, const float* __restrict__ Pb, float* __restrict__ out)
{
    const int row = blockIdx.x;
    const int tid = threadIdx.x;
    const int lane = tid & 63;
    const int wv = tid >> 6;
    const int beg = row * PAD;
    int deg = rowFill[row];
    if (deg > PAD) deg = PAD;

    __shared__ int tcol[PAD], teid[PAD], scol[PAD], spos[PAD], win[PAD];
    __shared__ float wgt[4][PAD];
    __shared__ float sdn[4];
    __shared__ float partv[4][4][64];
    __shared__ float rr[256];
    __shared__ float part2[4][64];

    for (int a = tid; a < deg; a += 256) { tcol[a] = edge_col[beg + a]; teid[a] = edge_eid[beg + a]; }
    __syncthreads();
    for (int a = tid; a < deg; a += 256) {
        const int e = teid[a];
        int r = 0;
        for (int b = 0; b < deg; ++b) r += (teid[b] < e);
        scol[r] = tcol[a];
        spos[r] = a;
    }
    __syncthreads();
    for (int a = tid; a < deg; a += 256) {
        const int c = scol[a];
        int wn = 1;
        for (int b = a + 1; b < deg; ++b) if (scol[b] == c) { wn = 0; break; }
        win[a] = wn;
    }
    __syncthreads();

    // softmax: wave wv handles head wv
    float m = -1e30f;
    for (int a = lane; a < deg; a += 64)
        if (win[a]) m = fmaxf(m, S[(size_t)(beg + spos[a]) * H + wv]);
#pragma unroll
    for (int off = 32; off; off >>= 1) m = fmaxf(m, __shfl_xor(m, off, 64));

    float dn = 0.f;
    for (int a = lane; a < deg; a += 64) {
        const float wvv = win[a] ? __expf(S[(size_t)(beg + spos[a]) * H + wv] - m) : 0.f;
        wgt[wv][a] = wvv;
        dn += wvv;
    }
#pragma unroll
    for (int off = 32; off; off >>= 1) dn += __shfl_xor(dn, off, 64);
    if (lane == 0) sdn[wv] = dn;
    __syncthreads();

    // PV: wave wv covers edges a = wv, wv+4, ...; each V row loaded once, used by all 4 heads
    float pv0 = 0.f, pv1 = 0.f, pv2 = 0.f, pv3 = 0.f;
    for (int a = wv; a < deg; a += 4) {
        const float vr = V[(size_t)scol[a] * D + lane];
        pv0 += wgt[0][a] * vr;
        pv1 += wgt[1][a] * vr;
        pv2 += wgt[2][a] * vr;
        pv3 += wgt[3][a] * vr;
    }
    partv[wv][0][lane] = pv0;
    partv[wv][1][lane] = pv1;
    partv[wv][2][lane] = pv2;
    partv[wv][3][lane] = pv3;
    __syncthreads();

    // reduce partials: wave wv owns head wv
    rr[wv * 64 + lane] = (partv[0][wv][lane] + partv[1][wv][lane]
                        + partv[2][wv][lane] + partv[3][wv][lane]) / sdn[wv];
    __syncthreads();

    // fused projection
    {
        float sps = 0.f;
#pragma unroll 8
        for (int k = 0; k < 64; ++k) sps += rr[wv * 64 + k] * Pw[(wv * 64 + k) * D + lane];
        part2[wv][lane] = sps;
    }
    __syncthreads();
    if (tid < 64)
        out[(size_t)row * D + tid] = part2[0][tid] + part2[1][tid] + part2[2][tid] + part2[3][tid] + Pb[tid];
}

extern "C" void kernel_launch(void* const* d_in, const int* in_sizes, int n_in,
                              void* d_out, int out_size, void* d_ws, size_t ws_size,
                              hipStream_t stream)
{
    const float* emb = (const float*)d_in[0];
    const float* Qw  = (const float*)d_in[1];
    const float* Qb  = (const float*)d_in[2];
    const float* Kw  = (const float*)d_in[3];
    const float* Kb  = (const float*)d_in[4];
    const float* Vw  = (const float*)d_in[5];
    const float* Vb  = (const float*)d_in[6];
    const float* W0  = (const float*)d_in[7];
    const float* b0  = (const float*)d_in[8];
    const float* W1  = (const float*)d_in[9];
    const float* b1  = (const float*)d_in[10];
    const float* W2  = (const float*)d_in[11];
    const float* b2  = (const float*)d_in[12];
    const float* Pw  = (const float*)d_in[13];
    const float* Pb  = (const float*)d_in[14];
    const int* src   = (const int*)d_in[15];
    const int* dst   = (const int*)d_in[16];
    const int* bond  = (const int*)d_in[17];

    const int N  = in_sizes[0] / D;
    const int Ep = in_sizes[15];
    const int TE = 2 * Ep;
    const int nblk = (TE + 255) / 256;
    const int nq8 = (N + 7) / 8;
    const int nhist = (nblk + 3) / 4;
    const int maxTiles = (TE + 63) / 64 + NB;

    char* w = (char*)d_ws;
    auto alloc = [&](size_t bytes) -> void* {
        void* p = (void*)w;
        w += ((bytes + 255) / 256) * 256;
        return p;
    };
    unsigned short* Qbf = (unsigned short*)alloc((size_t)N * D * 2);
    unsigned short* Kbf = (unsigned short*)alloc((size_t)N * D * 2);
    float* V        = (float*)alloc((size_t)N * D * 4);
    unsigned short* W0p = (unsigned short*)alloc((size_t)131072 * 2);
    unsigned short* W1p = (unsigned short*)alloc((size_t)65536 * 2);
    float* S        = (float*)alloc((size_t)N * PAD * H * 4);
    int* edge_col   = (int*)alloc((size_t)N * PAD * 4);
    int* edge_eid   = (int*)alloc((size_t)N * PAD * 4);
    int* bond_edges = (int*)alloc((size_t)TE * 4);
    int* padPos     = (int*)alloc((size_t)TE * 4);
    int* blockBondCnt = (int*)alloc((size_t)NB * nblk * 4);
    int* bondOff    = (int*)alloc((size_t)(NB + 1) * 4);
    int* rowFill    = (int*)alloc((size_t)N * 4);
    int* tileBt     = (int*)alloc((size_t)maxTiles * 4);
    int* tileT0     = (int*)alloc((size_t)maxTiles * 4);
    int* ntiles     = (int*)alloc(256);
    if ((size_t)(w - (char*)d_ws) > ws_size) return;

    prep_kernel<<<nq8 + 128 + nhist, 256, 0, stream>>>(
        emb, Qw, Qb, Kw, Kb, Vw, Vb, Qbf, Kbf, V, W0, W1, W0p, W1p,
        bond, Ep, TE, rowFill, blockBondCnt, nblk, N, nq8);
    scatter_kernel<<<nblk, 256, 0, stream>>>(
        src, dst, bond, Ep, TE, nblk, blockBondCnt, rowFill,
        edge_col, edge_eid, padPos, bond_edges, bondOff, tileBt, tileT0, ntiles);
    mlp_kernel<<<maxTiles, 256, 0, stream>>>(
        Qbf, Kbf, src, dst, Ep, bondOff, bond_edges, padPos, tileBt, tileT0, ntiles,
        W0p, W1p, b0, b1, W2, b2, S);
    agg_kernel<<<N, 256, 0, stream>>>(
        V, S, rowFill, edge_col, edge_eid, Pw, Pb, (float*)d_out);
}